// Round 7
// baseline (11031.561 us; speedup 1.0000x reference)
//
#include <hip/hip_runtime.h>
#include <math.h>

#define N_WORDS 16384
#define MAX_CHARS 16
#define CE 32
#define H1 64
#define WE 64
#define H2 128
#define N_TAGS 64

typedef _Float16 f16x8 __attribute__((ext_vector_type(8)));
typedef float f32x4 __attribute__((ext_vector_type(4)));
typedef int i32x8 __attribute__((ext_vector_type(8)));

__device__ __forceinline__ float sigf(float x) { return 1.0f / (1.0f + __expf(-x)); }
// saturation exact through v_exp/v_rcp: x->+inf: e=inf -> 1; x->-inf: e=0 -> -1
__device__ __forceinline__ float tanh2(float x) {
    float e = __expf(2.f * x);
    return 1.f - 2.f / (e + 1.f);
}
__device__ __forceinline__ float extq(f32x4 a, int q) {
    return (q == 0) ? a[0] : (q == 1) ? a[1] : (q == 2) ? a[2] : a[3];
}

// ---------------- Kernel 1: char LSTM, one wave per word, 16 words/block ----
extern "C" __global__ void __launch_bounds__(1024)
char_lstm_kernel(const int* __restrict__ char_ids, const int* __restrict__ char_lens,
                 const float* __restrict__ char_emb,
                 const float* __restrict__ Wih1, const float* __restrict__ Whh1,
                 const float* __restrict__ bih1, const float* __restrict__ bhh1,
                 float* __restrict__ h_char)
{
    extern __shared__ float lds[];
    float* Wc = lds;               // 256*97
    float* b1 = Wc + 256 * 97;     // 256
    float* xh = b1 + 256;          // 16*97
    const int tid = threadIdx.x;

    for (int idx = tid; idx < 256 * 96; idx += 1024) {
        int r = idx / 96, k = idx - r * 96;
        float v = (k < CE) ? Wih1[r * CE + k] : Whh1[r * H1 + (k - CE)];
        Wc[r * 97 + k] = v;
    }
    for (int r = tid; r < 256; r += 1024) b1[r] = bih1[r] + bhh1[r];
    __syncthreads();

    const int wlocal = tid >> 6;   // 0..15
    const int lane   = tid & 63;
    const int word   = blockIdx.x * 16 + wlocal;
    const int len    = char_lens[word];
    float h = 0.f, c = 0.f;
    float* xhw = xh + wlocal * 97;

    for (int t = 0; t < MAX_CHARS; ++t) {
        int cid = char_ids[word * MAX_CHARS + t];
        if (lane < CE) xhw[lane] = char_emb[cid * CE + lane];
        xhw[CE + lane] = h;
        __syncthreads();

        float a0 = 0.f, a1 = 0.f, a2 = 0.f, a3 = 0.f;
        const float* w0 = Wc + (0 * 64 + lane) * 97;
        const float* w1 = Wc + (1 * 64 + lane) * 97;
        const float* w2 = Wc + (2 * 64 + lane) * 97;
        const float* w3 = Wc + (3 * 64 + lane) * 97;
        #pragma unroll 8
        for (int k = 0; k < 96; ++k) {
            float x = xhw[k];
            a0 += w0[k] * x; a1 += w1[k] * x; a2 += w2[k] * x; a3 += w3[k] * x;
        }
        float pi = a0 + b1[lane];
        float pf = a1 + b1[64 + lane];
        float pg = a2 + b1[128 + lane];
        float po = a3 + b1[192 + lane];
        if (t < len) {
            float ig = sigf(pi), fg = sigf(pf), gg = tanhf(pg), og = sigf(po);
            c = fg * c + ig * gg;
            h = og * tanhf(c);
        }
        __syncthreads();
    }
    h_char[word * H1 + lane] = h;
}

// ---------------- Kernel 2: xpre = [word_emb | h_char] @ Wih2^T + b2 --------
// OUTPUT TRANSPOSED for kernel 3: xpre_t[t][hid*4 + g]  (g = col>>7, hid = col&127)
extern "C" __global__ void __launch_bounds__(256)
xpre_gemm_kernel(const int* __restrict__ word_ids, const float* __restrict__ word_emb,
                 const float* __restrict__ h_char,
                 const float* __restrict__ Wih2,
                 const float* __restrict__ bih2, const float* __restrict__ bhh2,
                 float* __restrict__ xpre)
{
    __shared__ float Wl[64 * 130];
    __shared__ float Xl[32 * 130];
    const int tid = threadIdx.x;
    const int wb = blockIdx.x * 32;   // word base
    const int cb = blockIdx.y * 64;   // col base

    for (int idx = tid; idx < 64 * 128; idx += 256) {
        int r = idx >> 7, k = idx & 127;
        Wl[r * 130 + k] = Wih2[(cb + r) * H2 + k];
    }
    for (int idx = tid; idx < 32 * 128; idx += 256) {
        int w = idx >> 7, k = idx & 127;
        float v = (k < WE) ? word_emb[(long)word_ids[wb + w] * WE + k]
                           : h_char[(long)(wb + w) * H1 + (k - WE)];
        Xl[w * 130 + k] = v;
    }
    __syncthreads();

    const int tc = tid & 31;
    const int wg = tid >> 5;          // 0..7
    float acc[4][2] = {};
    for (int k = 0; k < 128; ++k) {
        float wv0 = Wl[tc * 130 + k];
        float wv1 = Wl[(tc + 32) * 130 + k];
        #pragma unroll
        for (int i = 0; i < 4; ++i) {
            float x = Xl[(wg * 4 + i) * 130 + k];
            acc[i][0] += x * wv0;
            acc[i][1] += x * wv1;
        }
    }
    int c0 = cb + tc, c1 = cb + tc + 32;
    float b0 = bih2[c0] + bhh2[c0];
    float b1v = bih2[c1] + bhh2[c1];
    int o0 = (c0 & 127) * 4 + (c0 >> 7);
    int o1 = (c1 & 127) * 4 + (c1 >> 7);
    #pragma unroll
    for (int i = 0; i < 4; ++i) {
        long w = wb + wg * 4 + i;
        xpre[w * 512 + o0] = acc[i][0] + b0;
        xpre[w * 512 + o1] = acc[i][1] + b1v;
    }
}

// ---------------- Kernel 3: word LSTM, fp8 K=128 MFMA, 8-deep prefetch -----
__device__ __forceinline__ float lstm_step(
    const i32x8* af8, const unsigned char* h8r, unsigned char* h8w,
    float4 xp, float& c, int lg, int q, int hidx, bool writer)
{
    const f32x4 zf = {0.f, 0.f, 0.f, 0.f};
    i32x8 bf = *(const i32x8*)(h8r + lg * 32);
    f32x4 acc[4];
    #pragma unroll
    for (int g = 0; g < 4; ++g)
        acc[g] = __builtin_amdgcn_mfma_scale_f32_16x16x128_f8f6f4(
            af8[g], bf, zf, 0, 0, 0, 0x7F7F7F7F, 0, 0x7F7F7F7F);
    float p0 = extq(acc[0], q) + xp.x;
    float p1 = extq(acc[1], q) + xp.y;
    float p2 = extq(acc[2], q) + xp.z;
    float p3 = extq(acc[3], q) + xp.w;
    float ig = sigf(p0), fg = sigf(p1);
    float gg = tanh2(p2), og = sigf(p3);
    c = fg * c + ig * gg;
    float hn = og * tanh2(c);
    if (writer) {
        int hp = __builtin_amdgcn_cvt_pk_fp8_f32(hn, hn, 0, false);
        h8w[hidx] = (unsigned char)hp;
    }
    asm volatile("s_waitcnt lgkmcnt(0)" ::: "memory");
    __builtin_amdgcn_sched_barrier(0);
    __builtin_amdgcn_s_barrier();
    __builtin_amdgcn_sched_barrier(0);
    return hn;
}

extern "C" __global__ void __launch_bounds__(512)
word_lstm_kernel(const float* __restrict__ xpre, const float* __restrict__ Whh2,
                 float* __restrict__ hs)
{
    __shared__ __align__(16) unsigned char h8[2][128];
    const int tid = threadIdx.x;
    const int w   = tid >> 6;      // wave 0..7
    const int l   = tid & 63;
    const int lg  = l >> 4;        // k-chunk 0..3 (32 bytes each)
    const int lr  = l & 15;        // A-operand row-in-tile
    const int q   = l & 3;         // accumulator reg select
    const int hidx = 16 * w + (lg << 2) + q;   // this lane's h row [0,128)
    const bool writer = (lr < 4);

    // A-fragments fp8: af8[g] byte e = fp8(Whh2[g*128 + 16w + lr][lg*32 + e])
    i32x8 af8[4];
    #pragma unroll
    for (int g = 0; g < 4; ++g) {
        const float* wrow = Whh2 + (size_t)(g * 128 + 16 * w + lr) * 128 + lg * 32;
        i32x8 a;
        #pragma unroll
        for (int r = 0; r < 8; ++r) {
            int pk = __builtin_amdgcn_cvt_pk_fp8_f32(wrow[r * 4 + 0], wrow[r * 4 + 1], 0, false);
            pk = __builtin_amdgcn_cvt_pk_fp8_f32(wrow[r * 4 + 2], wrow[r * 4 + 3], pk, true);
            a[r] = pk;
        }
        af8[g] = a;
    }

    // 8-deep ping-pong xpre prefetch: xpA = steps tb..tb+7, xpB = tb+8..tb+15
    float4 xpA[8], xpB[8];
    #pragma unroll
    for (int j = 0; j < 8; ++j) {
        xpA[j] = *(const float4*)(xpre + (size_t)j * 512 + hidx * 4);
        xpB[j] = *(const float4*)(xpre + (size_t)(8 + j) * 512 + hidx * 4);
    }
    if (tid < 128) h8[0][tid] = 0;
    float c = 0.f;
    float hbuf[8];
    __syncthreads();

    for (int rnd = 0; rnd < N_WORDS / 16; ++rnd) {
        const int tb = rnd * 16;
        // ---- phase A: steps tb .. tb+7 (xpA consumed) ----
        #pragma unroll
        for (int j = 0; j < 8; ++j)
            hbuf[j] = lstm_step(af8, h8[j & 1], h8[(j + 1) & 1],
                                xpA[j], c, lg, q, hidx, writer);
        // reload xpA <- steps tb+16 .. tb+23 (consumed next round; ~8 steps slack)
        #pragma unroll
        for (int j = 0; j < 8; ++j) {
            int tt = (tb + 16 + j) & (N_WORDS - 1);
            xpA[j] = *(const float4*)(xpre + (size_t)tt * 512 + hidx * 4);
        }
        if (writer) {
            #pragma unroll
            for (int jj = 0; jj < 8; ++jj)
                hs[(size_t)(tb + jj) * 128 + hidx] = hbuf[jj];
        }
        // ---- phase B: steps tb+8 .. tb+15 (xpB consumed) ----
        #pragma unroll
        for (int j = 0; j < 8; ++j)
            hbuf[j] = lstm_step(af8, h8[j & 1], h8[(j + 1) & 1],
                                xpB[j], c, lg, q, hidx, writer);
        // reload xpB <- steps tb+24 .. tb+31
        #pragma unroll
        for (int j = 0; j < 8; ++j) {
            int tt = (tb + 24 + j) & (N_WORDS - 1);
            xpB[j] = *(const float4*)(xpre + (size_t)tt * 512 + hidx * 4);
        }
        if (writer) {
            #pragma unroll
            for (int jj = 0; jj < 8; ++jj)
                hs[(size_t)(tb + 8 + jj) * 128 + hidx] = hbuf[jj];
        }
    }
}

// ---------------- Kernel 4: logits + log_softmax, wave per word ------------
extern "C" __global__ void __launch_bounds__(256)
tag_kernel(const float* __restrict__ hs, const float* __restrict__ Wtag,
           const float* __restrict__ btag, float* __restrict__ out)
{
    __shared__ float Wl[64 * 129];
    const int tid = threadIdx.x;
    for (int idx = tid; idx < 64 * 128; idx += 256) {
        int r = idx >> 7, k = idx & 127;
        Wl[r * 129 + k] = Wtag[r * H2 + k];
    }
    __syncthreads();

    const int lane = tid & 63;
    const int word = blockIdx.x * 4 + (tid >> 6);
    const float* hrow = hs + (long)word * H2;
    float acc = btag[lane];
    #pragma unroll 4
    for (int k = 0; k < 128; ++k) acc += Wl[lane * 129 + k] * hrow[k];

    float m = acc;
    #pragma unroll
    for (int off = 32; off > 0; off >>= 1) m = fmaxf(m, __shfl_xor(m, off));
    float e = expf(acc - m);
    float s = e;
    #pragma unroll
    for (int off = 32; off > 0; off >>= 1) s += __shfl_xor(s, off);
    out[(long)word * N_TAGS + lane] = acc - m - logf(s);
}

extern "C" void kernel_launch(void* const* d_in, const int* in_sizes, int n_in,
                              void* d_out, int out_size, void* d_ws, size_t ws_size,
                              hipStream_t stream)
{
    (void)in_sizes; (void)n_in; (void)out_size; (void)ws_size;
    const int*   char_ids  = (const int*)d_in[0];
    const int*   word_ids  = (const int*)d_in[1];
    const int*   char_lens = (const int*)d_in[2];
    const float* char_emb  = (const float*)d_in[3];
    const float* word_emb  = (const float*)d_in[4];
    const float* Wih1 = (const float*)d_in[5];
    const float* Whh1 = (const float*)d_in[6];
    const float* bih1 = (const float*)d_in[7];
    const float* bhh1 = (const float*)d_in[8];
    const float* Wih2 = (const float*)d_in[9];
    const float* Whh2 = (const float*)d_in[10];
    const float* bih2 = (const float*)d_in[11];
    const float* bhh2 = (const float*)d_in[12];
    const float* Wtag = (const float*)d_in[13];
    const float* btag = (const float*)d_in[14];
    float* out = (float*)d_out;

    float* h_char = (float*)d_ws;                          // 16384*64
    float* xpre   = h_char + (size_t)N_WORDS * H1;         // 16384*512 (transposed)
    float* hs     = xpre + (size_t)N_WORDS * 512;          // 16384*128

    const int k1_lds = (256 * 97 + 256 + 16 * 97) * 4;     // 106560 B
    hipFuncSetAttribute((const void*)char_lstm_kernel,
                        hipFuncAttributeMaxDynamicSharedMemorySize, k1_lds);

    char_lstm_kernel<<<N_WORDS / 16, 1024, k1_lds, stream>>>(
        char_ids, char_lens, char_emb, Wih1, Whh1, bih1, bhh1, h_char);

    dim3 g2(N_WORDS / 32, 8);
    xpre_gemm_kernel<<<g2, 256, 0, stream>>>(
        word_ids, word_emb, h_char, Wih2, bih2, bhh2, xpre);

    word_lstm_kernel<<<1, 512, 0, stream>>>(xpre, Whh2, hs);

    tag_kernel<<<N_WORDS / 4, 256, 0, stream>>>(hs, Wtag, btag, out);
}

// Round 8
// 9064.272 us; speedup vs baseline: 1.2170x; 1.2170x over previous
//
#include <hip/hip_runtime.h>
#include <math.h>

#define N_WORDS 16384
#define MAX_CHARS 16
#define CE 32
#define H1 64
#define WE 64
#define H2 128
#define N_TAGS 64

typedef _Float16 f16x8 __attribute__((ext_vector_type(8)));
typedef float f32x4 __attribute__((ext_vector_type(4)));
typedef int i32x8 __attribute__((ext_vector_type(8)));

__device__ __forceinline__ float sigf(float x) { return 1.0f / (1.0f + __expf(-x)); }
// saturation exact through v_exp/v_rcp: x->+inf: e=inf -> 1; x->-inf: e=0 -> -1
__device__ __forceinline__ float tanh2(float x) {
    float e = __expf(2.f * x);
    return 1.f - 2.f / (e + 1.f);
}

// ---------------- Kernel 1: char LSTM, one wave per word, 16 words/block ----
extern "C" __global__ void __launch_bounds__(1024)
char_lstm_kernel(const int* __restrict__ char_ids, const int* __restrict__ char_lens,
                 const float* __restrict__ char_emb,
                 const float* __restrict__ Wih1, const float* __restrict__ Whh1,
                 const float* __restrict__ bih1, const float* __restrict__ bhh1,
                 float* __restrict__ h_char)
{
    extern __shared__ float lds[];
    float* Wc = lds;               // 256*97
    float* b1 = Wc + 256 * 97;     // 256
    float* xh = b1 + 256;          // 16*97
    const int tid = threadIdx.x;

    for (int idx = tid; idx < 256 * 96; idx += 1024) {
        int r = idx / 96, k = idx - r * 96;
        float v = (k < CE) ? Wih1[r * CE + k] : Whh1[r * H1 + (k - CE)];
        Wc[r * 97 + k] = v;
    }
    for (int r = tid; r < 256; r += 1024) b1[r] = bih1[r] + bhh1[r];
    __syncthreads();

    const int wlocal = tid >> 6;   // 0..15
    const int lane   = tid & 63;
    const int word   = blockIdx.x * 16 + wlocal;
    const int len    = char_lens[word];
    float h = 0.f, c = 0.f;
    float* xhw = xh + wlocal * 97;

    for (int t = 0; t < MAX_CHARS; ++t) {
        int cid = char_ids[word * MAX_CHARS + t];
        if (lane < CE) xhw[lane] = char_emb[cid * CE + lane];
        xhw[CE + lane] = h;
        __syncthreads();

        float a0 = 0.f, a1 = 0.f, a2 = 0.f, a3 = 0.f;
        const float* w0 = Wc + (0 * 64 + lane) * 97;
        const float* w1 = Wc + (1 * 64 + lane) * 97;
        const float* w2 = Wc + (2 * 64 + lane) * 97;
        const float* w3 = Wc + (3 * 64 + lane) * 97;
        #pragma unroll 8
        for (int k = 0; k < 96; ++k) {
            float x = xhw[k];
            a0 += w0[k] * x; a1 += w1[k] * x; a2 += w2[k] * x; a3 += w3[k] * x;
        }
        float pi = a0 + b1[lane];
        float pf = a1 + b1[64 + lane];
        float pg = a2 + b1[128 + lane];
        float po = a3 + b1[192 + lane];
        if (t < len) {
            float ig = sigf(pi), fg = sigf(pf), gg = tanhf(pg), og = sigf(po);
            c = fg * c + ig * gg;
            h = og * tanhf(c);
        }
        __syncthreads();
    }
    h_char[word * H1 + lane] = h;
}

// ---------------- Kernel 2: xpre = [word_emb | h_char] @ Wih2^T + b2 --------
// OUTPUT TRANSPOSED for kernel 3: xpre_t[t][hid*4 + g]  (g = col>>7, hid = col&127)
extern "C" __global__ void __launch_bounds__(256)
xpre_gemm_kernel(const int* __restrict__ word_ids, const float* __restrict__ word_emb,
                 const float* __restrict__ h_char,
                 const float* __restrict__ Wih2,
                 const float* __restrict__ bih2, const float* __restrict__ bhh2,
                 float* __restrict__ xpre)
{
    __shared__ float Wl[64 * 130];
    __shared__ float Xl[32 * 130];
    const int tid = threadIdx.x;
    const int wb = blockIdx.x * 32;   // word base
    const int cb = blockIdx.y * 64;   // col base

    for (int idx = tid; idx < 64 * 128; idx += 256) {
        int r = idx >> 7, k = idx & 127;
        Wl[r * 130 + k] = Wih2[(cb + r) * H2 + k];
    }
    for (int idx = tid; idx < 32 * 128; idx += 256) {
        int w = idx >> 7, k = idx & 127;
        float v = (k < WE) ? word_emb[(long)word_ids[wb + w] * WE + k]
                           : h_char[(long)(wb + w) * H1 + (k - WE)];
        Xl[w * 130 + k] = v;
    }
    __syncthreads();

    const int tc = tid & 31;
    const int wg = tid >> 5;          // 0..7
    float acc[4][2] = {};
    for (int k = 0; k < 128; ++k) {
        float wv0 = Wl[tc * 130 + k];
        float wv1 = Wl[(tc + 32) * 130 + k];
        #pragma unroll
        for (int i = 0; i < 4; ++i) {
            float x = Xl[(wg * 4 + i) * 130 + k];
            acc[i][0] += x * wv0;
            acc[i][1] += x * wv1;
        }
    }
    int c0 = cb + tc, c1 = cb + tc + 32;
    float b0 = bih2[c0] + bhh2[c0];
    float b1v = bih2[c1] + bhh2[c1];
    int o0 = (c0 & 127) * 4 + (c0 >> 7);
    int o1 = (c1 & 127) * 4 + (c1 >> 7);
    #pragma unroll
    for (int i = 0; i < 4; ++i) {
        long w = wb + wg * 4 + i;
        xpre[w * 512 + o0] = acc[i][0] + b0;
        xpre[w * 512 + o1] = acc[i][1] + b1v;
    }
}

// ---------------- Kernel 3: word LSTM, fp8 K=128 MFMA (swapped operands) ---
// Wave w owns rows [16w,16w+16). pre^T = h_dup @ U^T: A = h broadcast rows,
// B = U^T tile (af8 registers, same bytes as before). D[r][col] = pre[16w+col]
// for ALL r -> lane picks acc[g][0], col = l&15. Zero extraction cndmasks.
extern "C" __global__ void __launch_bounds__(512)
word_lstm_kernel(const float* __restrict__ xpre, const float* __restrict__ Whh2,
                 float* __restrict__ hs)
{
    __shared__ __align__(16) unsigned char h8[2][128];
    const int tid = threadIdx.x;
    const int w   = tid >> 6;      // wave 0..7
    const int l   = tid & 63;
    const int lg  = l >> 4;        // k-chunk 0..3 (32 bytes each)
    const int lc  = l & 15;        // output column = row index within wave block
    const int hidx = 16 * w + lc;  // this lane's h row [0,128)
    const bool writer = (l < 16);

    // U^T fragments fp8 (B operand): byte e of lane l = fp8(U[16w+lc][lg*32+e])
    i32x8 af8[4];
    #pragma unroll
    for (int g = 0; g < 4; ++g) {
        const float* wrow = Whh2 + (size_t)(g * 128 + hidx) * 128 + lg * 32;
        i32x8 a;
        #pragma unroll
        for (int r = 0; r < 8; ++r) {
            int pk = __builtin_amdgcn_cvt_pk_fp8_f32(wrow[r * 4 + 0], wrow[r * 4 + 1], 0, false);
            pk = __builtin_amdgcn_cvt_pk_fp8_f32(wrow[r * 4 + 2], wrow[r * 4 + 3], pk, true);
            a[r] = pk;
        }
        af8[g] = a;
    }
    if (tid < 128) h8[0][tid] = 0;
    float c = 0.f;
    float4 xp = *(const float4*)(xpre + hidx * 4);   // t = 0 (transposed layout)
    float hbuf[8];
    const f32x4 zf = {0.f, 0.f, 0.f, 0.f};
    __syncthreads();

    for (int t8 = 0; t8 < N_WORDS / 8; ++t8) {
        #pragma unroll
        for (int j = 0; j < 8; ++j) {
            const int t = t8 * 8 + j;
            const int tn = (t + 1) & (N_WORDS - 1);
            // independent global prefetch — stays in flight across the barrier
            float4 xpn = *(const float4*)(xpre + (size_t)tn * 512 + hidx * 4);

            // A operand: h chunk broadcast (all 16 A-rows identical)
            const unsigned char* hb = h8[j & 1] + lg * 32;
            i32x8 bf = *(const i32x8*)hb;          // 2x ds_read_b128

            f32x4 acc[4];
            #pragma unroll
            for (int g = 0; g < 4; ++g)
                acc[g] = __builtin_amdgcn_mfma_scale_f32_16x16x128_f8f6f4(
                    bf, af8[g], zf, 0, 0, 0, 0x7F7F7F7F, 0, 0x7F7F7F7F);

            float p0 = acc[0][0] + xp.x;
            float p1 = acc[1][0] + xp.y;
            float p2 = acc[2][0] + xp.z;
            float p3 = acc[3][0] + xp.w;
            float ig = sigf(p0), fg = sigf(p1);
            float gg = tanh2(p2), og = sigf(p3);
            c = fg * c + ig * gg;
            float hn = og * tanh2(c);
            hbuf[j] = hn;
            if (writer) {
                int hp = __builtin_amdgcn_cvt_pk_fp8_f32(hn, hn, 0, false);
                h8[(j + 1) & 1][hidx] = (unsigned char)hp;
            }
            xp = xpn;

            // raw barrier: drain LDS only, leave the global prefetch in flight
            asm volatile("s_waitcnt lgkmcnt(0)" ::: "memory");
            __builtin_amdgcn_sched_barrier(0);
            __builtin_amdgcn_s_barrier();
            __builtin_amdgcn_sched_barrier(0);
        }
        // stores overlap the next step's ds_read latency
        if (writer) {
            #pragma unroll
            for (int jj = 0; jj < 8; ++jj)
                hs[(size_t)(t8 * 8 + jj) * 128 + hidx] = hbuf[jj];
        }
    }
}

// ---------------- Kernel 4: logits + log_softmax, wave per word ------------
extern "C" __global__ void __launch_bounds__(256)
tag_kernel(const float* __restrict__ hs, const float* __restrict__ Wtag,
           const float* __restrict__ btag, float* __restrict__ out)
{
    __shared__ float Wl[64 * 129];
    const int tid = threadIdx.x;
    for (int idx = tid; idx < 64 * 128; idx += 256) {
        int r = idx >> 7, k = idx & 127;
        Wl[r * 129 + k] = Wtag[r * H2 + k];
    }
    __syncthreads();

    const int lane = tid & 63;
    const int word = blockIdx.x * 4 + (tid >> 6);
    const float* hrow = hs + (long)word * H2;
    float acc = btag[lane];
    #pragma unroll 4
    for (int k = 0; k < 128; ++k) acc += Wl[lane * 129 + k] * hrow[k];

    float m = acc;
    #pragma unroll
    for (int off = 32; off > 0; off >>= 1) m = fmaxf(m, __shfl_xor(m, off));
    float e = expf(acc - m);
    float s = e;
    #pragma unroll
    for (int off = 32; off > 0; off >>= 1) s += __shfl_xor(s, off);
    out[(long)word * N_TAGS + lane] = acc - m - logf(s);
}

extern "C" void kernel_launch(void* const* d_in, const int* in_sizes, int n_in,
                              void* d_out, int out_size, void* d_ws, size_t ws_size,
                              hipStream_t stream)
{
    (void)in_sizes; (void)n_in; (void)out_size; (void)ws_size;
    const int*   char_ids  = (const int*)d_in[0];
    const int*   word_ids  = (const int*)d_in[1];
    const int*   char_lens = (const int*)d_in[2];
    const float* char_emb  = (const float*)d_in[3];
    const float* word_emb  = (const float*)d_in[4];
    const float* Wih1 = (const float*)d_in[5];
    const float* Whh1 = (const float*)d_in[6];
    const float* bih1 = (const float*)d_in[7];
    const float* bhh1 = (const float*)d_in[8];
    const float* Wih2 = (const float*)d_in[9];
    const float* Whh2 = (const float*)d_in[10];
    const float* bih2 = (const float*)d_in[11];
    const float* bhh2 = (const float*)d_in[12];
    const float* Wtag = (const float*)d_in[13];
    const float* btag = (const float*)d_in[14];
    float* out = (float*)d_out;

    float* h_char = (float*)d_ws;                          // 16384*64
    float* xpre   = h_char + (size_t)N_WORDS * H1;         // 16384*512 (transposed)
    float* hs     = xpre + (size_t)N_WORDS * 512;          // 16384*128

    const int k1_lds = (256 * 97 + 256 + 16 * 97) * 4;     // 106560 B
    hipFuncSetAttribute((const void*)char_lstm_kernel,
                        hipFuncAttributeMaxDynamicSharedMemorySize, k1_lds);

    char_lstm_kernel<<<N_WORDS / 16, 1024, k1_lds, stream>>>(
        char_ids, char_lens, char_emb, Wih1, Whh1, bih1, bhh1, h_char);

    dim3 g2(N_WORDS / 32, 8);
    xpre_gemm_kernel<<<g2, 256, 0, stream>>>(
        word_ids, word_emb, h_char, Wih2, bih2, bhh2, xpre);

    word_lstm_kernel<<<1, 512, 0, stream>>>(xpre, Whh2, hs);

    tag_kernel<<<N_WORDS / 4, 256, 0, stream>>>(hs, Wtag, btag, out);
}

// Round 10
// 6368.653 us; speedup vs baseline: 1.7322x; 1.4233x over previous
//
#include <hip/hip_runtime.h>
#include <math.h>

#define N_WORDS 16384
#define MAX_CHARS 16
#define CE 32
#define H1 64
#define WE 64
#define H2 128
#define N_TAGS 64

typedef _Float16 f16x8 __attribute__((ext_vector_type(8)));
typedef float f32x4 __attribute__((ext_vector_type(4)));
typedef int i32x8 __attribute__((ext_vector_type(8)));

__device__ __forceinline__ float rcpf(float x) { return __builtin_amdgcn_rcpf(x); }
// sig(x) = rcp(1+e^-x): x->+inf e=0 -> rcp(1)=1; x->-inf e=inf -> rcp(inf)=0. exact sat.
__device__ __forceinline__ float sigf(float x) { return rcpf(1.0f + __expf(-x)); }
// tanh(x) = 1 - 2*rcp(e^{2x}+1): sat exact at +/-1.
__device__ __forceinline__ float tanh2(float x) {
    return 1.f - 2.f * rcpf(__expf(2.f * x) + 1.f);
}

// ---------------- Kernel 1: char LSTM, one wave per word, 16 words/block ----
extern "C" __global__ void __launch_bounds__(1024)
char_lstm_kernel(const int* __restrict__ char_ids, const int* __restrict__ char_lens,
                 const float* __restrict__ char_emb,
                 const float* __restrict__ Wih1, const float* __restrict__ Whh1,
                 const float* __restrict__ bih1, const float* __restrict__ bhh1,
                 float* __restrict__ h_char)
{
    extern __shared__ float lds[];
    float* Wc = lds;               // 256*97
    float* b1 = Wc + 256 * 97;     // 256
    float* xh = b1 + 256;          // 16*97
    const int tid = threadIdx.x;

    for (int idx = tid; idx < 256 * 96; idx += 1024) {
        int r = idx / 96, k = idx - r * 96;
        float v = (k < CE) ? Wih1[r * CE + k] : Whh1[r * H1 + (k - CE)];
        Wc[r * 97 + k] = v;
    }
    for (int r = tid; r < 256; r += 1024) b1[r] = bih1[r] + bhh1[r];
    __syncthreads();

    const int wlocal = tid >> 6;   // 0..15
    const int lane   = tid & 63;
    const int word   = blockIdx.x * 16 + wlocal;
    const int len    = char_lens[word];
    float h = 0.f, c = 0.f;
    float* xhw = xh + wlocal * 97;

    for (int t = 0; t < MAX_CHARS; ++t) {
        int cid = char_ids[word * MAX_CHARS + t];
        if (lane < CE) xhw[lane] = char_emb[cid * CE + lane];
        xhw[CE + lane] = h;
        __syncthreads();

        float a0 = 0.f, a1 = 0.f, a2 = 0.f, a3 = 0.f;
        const float* w0 = Wc + (0 * 64 + lane) * 97;
        const float* w1 = Wc + (1 * 64 + lane) * 97;
        const float* w2 = Wc + (2 * 64 + lane) * 97;
        const float* w3 = Wc + (3 * 64 + lane) * 97;
        #pragma unroll 8
        for (int k = 0; k < 96; ++k) {
            float x = xhw[k];
            a0 += w0[k] * x; a1 += w1[k] * x; a2 += w2[k] * x; a3 += w3[k] * x;
        }
        float pi = a0 + b1[lane];
        float pf = a1 + b1[64 + lane];
        float pg = a2 + b1[128 + lane];
        float po = a3 + b1[192 + lane];
        if (t < len) {
            float ig = sigf(pi), fg = sigf(pf), gg = tanh2(pg), og = sigf(po);
            c = fg * c + ig * gg;
            h = og * tanh2(c);
        }
        __syncthreads();
    }
    h_char[word * H1 + lane] = h;
}

// ---------------- Kernel 2: xpre = [word_emb | h_char] @ Wih2^T + b2 --------
// OUTPUT TRANSPOSED for kernel 3: xpre_t[t][hid*4 + g]  (g = col>>7, hid = col&127)
extern "C" __global__ void __launch_bounds__(256)
xpre_gemm_kernel(const int* __restrict__ word_ids, const float* __restrict__ word_emb,
                 const float* __restrict__ h_char,
                 const float* __restrict__ Wih2,
                 const float* __restrict__ bih2, const float* __restrict__ bhh2,
                 float* __restrict__ xpre)
{
    __shared__ float Wl[64 * 130];
    __shared__ float Xl[32 * 130];
    const int tid = threadIdx.x;
    const int wb = blockIdx.x * 32;   // word base
    const int cb = blockIdx.y * 64;   // col base

    for (int idx = tid; idx < 64 * 128; idx += 256) {
        int r = idx >> 7, k = idx & 127;
        Wl[r * 130 + k] = Wih2[(cb + r) * H2 + k];
    }
    for (int idx = tid; idx < 32 * 128; idx += 256) {
        int w = idx >> 7, k = idx & 127;
        float v = (k < WE) ? word_emb[(long)word_ids[wb + w] * WE + k]
                           : h_char[(long)(wb + w) * H1 + (k - WE)];
        Xl[w * 130 + k] = v;
    }
    __syncthreads();

    const int tc = tid & 31;
    const int wg = tid >> 5;          // 0..7
    float acc[4][2] = {};
    for (int k = 0; k < 128; ++k) {
        float wv0 = Wl[tc * 130 + k];
        float wv1 = Wl[(tc + 32) * 130 + k];
        #pragma unroll
        for (int i = 0; i < 4; ++i) {
            float x = Xl[(wg * 4 + i) * 130 + k];
            acc[i][0] += x * wv0;
            acc[i][1] += x * wv1;
        }
    }
    int c0 = cb + tc, c1 = cb + tc + 32;
    float b0 = bih2[c0] + bhh2[c0];
    float b1v = bih2[c1] + bhh2[c1];
    int o0 = (c0 & 127) * 4 + (c0 >> 7);
    int o1 = (c1 & 127) * 4 + (c1 >> 7);
    #pragma unroll
    for (int i = 0; i < 4; ++i) {
        long w = wb + wg * 4 + i;
        xpre[w * 512 + o0] = acc[i][0] + b0;
        xpre[w * 512 + o1] = acc[i][1] + b1v;
    }
}

// ---------------- Kernel 3: word LSTM, fp8 K=128 MFMA (swapped operands) ---
// Wave w owns rows [16w,16w+16). pre^T = h_dup @ U^T: A = h broadcast rows,
// B = U^T tile. D[r][col] = pre[16w+col] for ALL r -> lane picks acc[g][0],
// col = l&15. Gate math uses hardware v_rcp (1 ulp) instead of IEEE divide.
extern "C" __global__ void __launch_bounds__(512)
word_lstm_kernel(const float* __restrict__ xpre, const float* __restrict__ Whh2,
                 float* __restrict__ hs)
{
    __shared__ __align__(16) unsigned char h8[2][128];
    const int tid = threadIdx.x;
    const int w   = tid >> 6;      // wave 0..7
    const int l   = tid & 63;
    const int lg  = l >> 4;        // k-chunk 0..3 (32 bytes each)
    const int lc  = l & 15;        // output column = row index within wave block
    const int hidx = 16 * w + lc;  // this lane's h row [0,128)
    const bool writer = (l < 16);

    // U^T fragments fp8 (B operand): byte e of lane l = fp8(U[16w+lc][lg*32+e])
    i32x8 af8[4];
    #pragma unroll
    for (int g = 0; g < 4; ++g) {
        const float* wrow = Whh2 + (size_t)(g * 128 + hidx) * 128 + lg * 32;
        i32x8 a;
        #pragma unroll
        for (int r = 0; r < 8; ++r) {
            int pk = __builtin_amdgcn_cvt_pk_fp8_f32(wrow[r * 4 + 0], wrow[r * 4 + 1], 0, false);
            pk = __builtin_amdgcn_cvt_pk_fp8_f32(wrow[r * 4 + 2], wrow[r * 4 + 3], pk, true);
            a[r] = pk;
        }
        af8[g] = a;
    }
    if (tid < 128) h8[0][tid] = 0;
    float c = 0.f;
    float4 xp = *(const float4*)(xpre + hidx * 4);   // t = 0 (transposed layout)
    float hbuf[8];
    const f32x4 zf = {0.f, 0.f, 0.f, 0.f};
    __syncthreads();

    for (int t8 = 0; t8 < N_WORDS / 8; ++t8) {
        #pragma unroll
        for (int j = 0; j < 8; ++j) {
            const int t = t8 * 8 + j;
            const int tn = (t + 1) & (N_WORDS - 1);
            // independent global prefetch — stays in flight across the barrier
            float4 xpn = *(const float4*)(xpre + (size_t)tn * 512 + hidx * 4);

            // A operand: h chunk broadcast (all 16 A-rows identical)
            const unsigned char* hb = h8[j & 1] + lg * 32;
            i32x8 bf = *(const i32x8*)hb;          // 2x ds_read_b128

            f32x4 acc[4];
            #pragma unroll
            for (int g = 0; g < 4; ++g)
                acc[g] = __builtin_amdgcn_mfma_scale_f32_16x16x128_f8f6f4(
                    bf, af8[g], zf, 0, 0, 0, 0x7F7F7F7F, 0, 0x7F7F7F7F);

            float p0 = acc[0][0] + xp.x;
            float p1 = acc[1][0] + xp.y;
            float p2 = acc[2][0] + xp.z;
            float p3 = acc[3][0] + xp.w;
            float ig = sigf(p0), fg = sigf(p1);
            float gg = tanh2(p2), og = sigf(p3);
            c = fg * c + ig * gg;
            float hn = og * tanh2(c);
            hbuf[j] = hn;
            if (writer) {
                int hp = __builtin_amdgcn_cvt_pk_fp8_f32(hn, hn, 0, false);
                h8[(j + 1) & 1][hidx] = (unsigned char)hp;
            }
            xp = xpn;

            // raw barrier: drain LDS only, leave the global prefetch in flight
            asm volatile("s_waitcnt lgkmcnt(0)" ::: "memory");
            __builtin_amdgcn_sched_barrier(0);
            __builtin_amdgcn_s_barrier();
            __builtin_amdgcn_sched_barrier(0);
        }
        // stores overlap the next step's ds_read latency
        if (writer) {
            #pragma unroll
            for (int jj = 0; jj < 8; ++jj)
                hs[(size_t)(t8 * 8 + jj) * 128 + hidx] = hbuf[jj];
        }
    }
}

// ---------------- Kernel 4: logits + log_softmax, wave per word ------------
extern "C" __global__ void __launch_bounds__(256)
tag_kernel(const float* __restrict__ hs, const float* __restrict__ Wtag,
           const float* __restrict__ btag, float* __restrict__ out)
{
    __shared__ float Wl[64 * 129];
    const int tid = threadIdx.x;
    for (int idx = tid; idx < 64 * 128; idx += 256) {
        int r = idx >> 7, k = idx & 127;
        Wl[r * 129 + k] = Wtag[r * H2 + k];
    }
    __syncthreads();

    const int lane = tid & 63;
    const int word = blockIdx.x * 4 + (tid >> 6);
    const float* hrow = hs + (long)word * H2;
    float acc = btag[lane];
    #pragma unroll 4
    for (int k = 0; k < 128; ++k) acc += Wl[lane * 129 + k] * hrow[k];

    float m = acc;
    #pragma unroll
    for (int off = 32; off > 0; off >>= 1) m = fmaxf(m, __shfl_xor(m, off));
    float e = expf(acc - m);
    float s = e;
    #pragma unroll
    for (int off = 32; off > 0; off >>= 1) s += __shfl_xor(s, off);
    out[(long)word * N_TAGS + lane] = acc - m - logf(s);
}

extern "C" void kernel_launch(void* const* d_in, const int* in_sizes, int n_in,
                              void* d_out, int out_size, void* d_ws, size_t ws_size,
                              hipStream_t stream)
{
    (void)in_sizes; (void)n_in; (void)out_size; (void)ws_size;
    const int*   char_ids  = (const int*)d_in[0];
    const int*   word_ids  = (const int*)d_in[1];
    const int*   char_lens = (const int*)d_in[2];
    const float* char_emb  = (const float*)d_in[3];
    const float* word_emb  = (const float*)d_in[4];
    const float* Wih1 = (const float*)d_in[5];
    const float* Whh1 = (const float*)d_in[6];
    const float* bih1 = (const float*)d_in[7];
    const float* bhh1 = (const float*)d_in[8];
    const float* Wih2 = (const float*)d_in[9];
    const float* Whh2 = (const float*)d_in[10];
    const float* bih2 = (const float*)d_in[11];
    const float* bhh2 = (const float*)d_in[12];
    const float* Wtag = (const float*)d_in[13];
    const float* btag = (const float*)d_in[14];
    float* out = (float*)d_out;

    float* h_char = (float*)d_ws;                          // 16384*64
    float* xpre   = h_char + (size_t)N_WORDS * H1;         // 16384*512 (transposed)
    float* hs     = xpre + (size_t)N_WORDS * 512;          // 16384*128

    const int k1_lds = (256 * 97 + 256 + 16 * 97) * 4;     // 106560 B
    hipFuncSetAttribute((const void*)char_lstm_kernel,
                        hipFuncAttributeMaxDynamicSharedMemorySize, k1_lds);

    char_lstm_kernel<<<N_WORDS / 16, 1024, k1_lds, stream>>>(
        char_ids, char_lens, char_emb, Wih1, Whh1, bih1, bhh1, h_char);

    dim3 g2(N_WORDS / 32, 8);
    xpre_gemm_kernel<<<g2, 256, 0, stream>>>(
        word_ids, word_emb, h_char, Wih2, bih2, bhh2, xpre);

    word_lstm_kernel<<<1, 512, 0, stream>>>(xpre, Whh2, hs);

    tag_kernel<<<N_WORDS / 4, 256, 0, stream>>>(hs, Wtag, btag, out);
}

// Round 11
// 6280.079 us; speedup vs baseline: 1.7566x; 1.0141x over previous
//
#include <hip/hip_runtime.h>
#include <math.h>

#define N_WORDS 16384
#define MAX_CHARS 16
#define CE 32
#define H1 64
#define WE 64
#define H2 128
#define N_TAGS 64
#define LOG2E 1.44269504f
#define TWO_LOG2E 2.88539008f

typedef _Float16 f16x8 __attribute__((ext_vector_type(8)));
typedef float f32x4 __attribute__((ext_vector_type(4)));
typedef int i32x8 __attribute__((ext_vector_type(8)));

__device__ __forceinline__ float rcpf(float x) { return __builtin_amdgcn_rcpf(x); }
__device__ __forceinline__ float exp2f_hw(float x) { return __builtin_amdgcn_exp2f(x); }
// p is pre-scaled by log2e. sig = rcp(1+2^-p); sat exact (rcp(1)=1, rcp(inf)=0).
__device__ __forceinline__ float sig2(float p) { return rcpf(1.0f + exp2f_hw(-p)); }
// tanh of (p/log2e) given scaled p: 1 - 2*rcp(2^{2p}+1)
__device__ __forceinline__ float tanh2s(float p) {
    return 1.f - 2.f * rcpf(exp2f_hw(2.f * p) + 1.f);
}
// tanh of unscaled c
__device__ __forceinline__ float tanhc(float c) {
    return 1.f - 2.f * rcpf(exp2f_hw(TWO_LOG2E * c) + 1.f);
}

// ---------------- Kernel 0: prep — f16 weights (scaled by log2e) -----------
extern "C" __global__ void __launch_bounds__(256)
prep_kernel(const float* __restrict__ Wih1, const float* __restrict__ Whh1,
            const float* __restrict__ bih1, const float* __restrict__ bhh1,
            const float* __restrict__ char_emb,
            _Float16* __restrict__ W16, _Float16* __restrict__ ce16,
            float* __restrict__ b1s)
{
    int idx = blockIdx.x * 256 + threadIdx.x;
    if (idx < 256 * 96) {
        int r = idx / 96, k = idx - r * 96;
        float v = (k < CE) ? Wih1[r * CE + k] : Whh1[r * H1 + (k - CE)];
        W16[idx] = (_Float16)(v * LOG2E);
    }
    if (idx < 128 * 32) ce16[idx] = (_Float16)char_emb[idx];
    if (idx < 256) b1s[idx] = (bih1[idx] + bhh1[idx]) * LOG2E;
}

// ---------------- Kernel 1: char LSTM via batched f16 MFMA -----------------
// 16 words/block, 4 waves. Wave w owns units [16w,16w+16) for all 4 gates:
// B-frags (W^T) in 48 VGPRs, read once. Per step: A=[x|h] frags, 12 MFMA
// 16x16x32_f16 (bias folded into C). D: row=word=(l>>4)*4+q, col=unit=16w+lc.
// h double-buffered in LDS [16][72] f16 (stride-72 pad -> 2-way only).
extern "C" __global__ void __launch_bounds__(256)
char_lstm_kernel(const int* __restrict__ char_ids, const int* __restrict__ char_lens,
                 const _Float16* __restrict__ W16, const _Float16* __restrict__ ce16,
                 const float* __restrict__ b1s, float* __restrict__ h_char)
{
    __shared__ _Float16 hl[2][16 * 72];
    const int tid = threadIdx.x;
    const int w  = tid >> 6;        // wave 0..3 -> unit stripe
    const int l  = tid & 63;
    const int lg = l >> 4;          // k-subgroup 0..3
    const int lc = l & 15;          // A-row (word) for A-frags; D-col (unit)
    const int wb = blockIdx.x * 16;

    // B-frags: bfr[gt][kc] elem j = W16[gt*64+16w+lc][kc*32+lg*8+j]
    f16x8 bfr[4][3];
    #pragma unroll
    for (int gt = 0; gt < 4; ++gt)
        #pragma unroll
        for (int kc = 0; kc < 3; ++kc)
            bfr[gt][kc] = *(const f16x8*)(W16 + (size_t)(gt * 64 + 16 * w + lc) * 96
                                          + kc * 32 + lg * 8);
    float bb[4];
    #pragma unroll
    for (int gt = 0; gt < 4; ++gt) bb[gt] = b1s[gt * 64 + 16 * w + lc];

    // cid preload: word wb+lc, 16 chars
    int cids[16];
    {
        const int4* cp = (const int4*)(char_ids + (size_t)(wb + lc) * 16);
        #pragma unroll
        for (int i = 0; i < 4; ++i) {
            int4 v = cp[i];
            cids[i * 4 + 0] = v.x; cids[i * 4 + 1] = v.y;
            cids[i * 4 + 2] = v.z; cids[i * 4 + 3] = v.w;
        }
    }
    // len preload for this lane's 4 D-rows (words lg*4+q)
    int4 len4 = *(const int4*)(char_lens + wb + lg * 4);
    int lens[4] = {len4.x, len4.y, len4.z, len4.w};

    float hreg[4] = {0.f, 0.f, 0.f, 0.f};
    float creg[4] = {0.f, 0.f, 0.f, 0.f};
    for (int i = tid; i < 16 * 72; i += 256) hl[0][i] = (_Float16)0.f;
    __syncthreads();

    #pragma unroll
    for (int t = 0; t < MAX_CHARS; ++t) {
        const _Float16* hb = hl[t & 1];
        f16x8 ax  = *(const f16x8*)(ce16 + (size_t)cids[t] * 32 + lg * 8);
        f16x8 ah1 = *(const f16x8*)(hb + lc * 72 + lg * 8);
        f16x8 ah2 = *(const f16x8*)(hb + lc * 72 + 32 + lg * 8);
        f32x4 acc[4];
        #pragma unroll
        for (int gt = 0; gt < 4; ++gt) {
            f32x4 cb = {bb[gt], bb[gt], bb[gt], bb[gt]};
            acc[gt] = __builtin_amdgcn_mfma_f32_16x16x32_f16(ax,  bfr[gt][0], cb, 0, 0, 0);
            acc[gt] = __builtin_amdgcn_mfma_f32_16x16x32_f16(ah1, bfr[gt][1], acc[gt], 0, 0, 0);
            acc[gt] = __builtin_amdgcn_mfma_f32_16x16x32_f16(ah2, bfr[gt][2], acc[gt], 0, 0, 0);
        }
        #pragma unroll
        for (int q = 0; q < 4; ++q) {
            float ig = sig2(acc[0][q]);
            float fg = sig2(acc[1][q]);
            float gg = tanh2s(acc[2][q]);
            float og = sig2(acc[3][q]);
            float cn = fg * creg[q] + ig * gg;
            float hn = og * tanhc(cn);
            bool v = t < lens[q];
            creg[q] = v ? cn : creg[q];
            hreg[q] = v ? hn : hreg[q];
            hl[(t + 1) & 1][(lg * 4 + q) * 72 + 16 * w + lc] = (_Float16)hreg[q];
        }
        __syncthreads();
    }
    #pragma unroll
    for (int q = 0; q < 4; ++q)
        h_char[(size_t)(wb + lg * 4 + q) * H1 + 16 * w + lc] = hreg[q];
}

// ---------------- Kernel 2: xpre = [word_emb | h_char] @ Wih2^T + b2 --------
// OUTPUT TRANSPOSED + scaled by log2e: xpre_t[t][hid*4+g] (g=col>>7, hid=col&127)
extern "C" __global__ void __launch_bounds__(256)
xpre_gemm_kernel(const int* __restrict__ word_ids, const float* __restrict__ word_emb,
                 const float* __restrict__ h_char,
                 const float* __restrict__ Wih2,
                 const float* __restrict__ bih2, const float* __restrict__ bhh2,
                 float* __restrict__ xpre)
{
    __shared__ float Wl[64 * 130];
    __shared__ float Xl[32 * 130];
    const int tid = threadIdx.x;
    const int wb = blockIdx.x * 32;   // word base
    const int cb = blockIdx.y * 64;   // col base

    for (int idx = tid; idx < 64 * 128; idx += 256) {
        int r = idx >> 7, k = idx & 127;
        Wl[r * 130 + k] = Wih2[(cb + r) * H2 + k];
    }
    for (int idx = tid; idx < 32 * 128; idx += 256) {
        int w = idx >> 7, k = idx & 127;
        float v = (k < WE) ? word_emb[(long)word_ids[wb + w] * WE + k]
                           : h_char[(long)(wb + w) * H1 + (k - WE)];
        Xl[w * 130 + k] = v;
    }
    __syncthreads();

    const int tc = tid & 31;
    const int wg = tid >> 5;          // 0..7
    float acc[4][2] = {};
    for (int k = 0; k < 128; ++k) {
        float wv0 = Wl[tc * 130 + k];
        float wv1 = Wl[(tc + 32) * 130 + k];
        #pragma unroll
        for (int i = 0; i < 4; ++i) {
            float x = Xl[(wg * 4 + i) * 130 + k];
            acc[i][0] += x * wv0;
            acc[i][1] += x * wv1;
        }
    }
    int c0 = cb + tc, c1 = cb + tc + 32;
    float b0 = bih2[c0] + bhh2[c0];
    float b1v = bih2[c1] + bhh2[c1];
    int o0 = (c0 & 127) * 4 + (c0 >> 7);
    int o1 = (c1 & 127) * 4 + (c1 >> 7);
    #pragma unroll
    for (int i = 0; i < 4; ++i) {
        long w = wb + wg * 4 + i;
        xpre[w * 512 + o0] = (acc[i][0] + b0) * LOG2E;
        xpre[w * 512 + o1] = (acc[i][1] + b1v) * LOG2E;
    }
}

// ---------------- Kernel 3: word LSTM, fp8 K=128 MFMA (swapped operands) ---
// pre^T = h_dup @ U^T; xp folded into MFMA C operand; exp2-domain gates.
extern "C" __global__ void __launch_bounds__(512)
word_lstm_kernel(const float* __restrict__ xpre, const float* __restrict__ Whh2,
                 float* __restrict__ hs)
{
    __shared__ __align__(16) unsigned char h8[2][128];
    const int tid = threadIdx.x;
    const int w   = tid >> 6;      // wave 0..7
    const int l   = tid & 63;
    const int lg  = l >> 4;        // k-chunk 0..3 (32 bytes each)
    const int lc  = l & 15;        // output column = row index within wave block
    const int hidx = 16 * w + lc;  // this lane's h row [0,128)
    const bool writer = (l < 16);

    // U^T fragments fp8 (B operand), scaled by log2e before quantization
    i32x8 af8[4];
    #pragma unroll
    for (int g = 0; g < 4; ++g) {
        const float* wrow = Whh2 + (size_t)(g * 128 + hidx) * 128 + lg * 32;
        i32x8 a;
        #pragma unroll
        for (int r = 0; r < 8; ++r) {
            int pk = __builtin_amdgcn_cvt_pk_fp8_f32(
                wrow[r * 4 + 0] * LOG2E, wrow[r * 4 + 1] * LOG2E, 0, false);
            pk = __builtin_amdgcn_cvt_pk_fp8_f32(
                wrow[r * 4 + 2] * LOG2E, wrow[r * 4 + 3] * LOG2E, pk, true);
            a[r] = pk;
        }
        af8[g] = a;
    }
    if (tid < 128) h8[0][tid] = 0;
    float c = 0.f;
    float4 xp = *(const float4*)(xpre + hidx * 4);   // t = 0 (transposed layout)
    float hbuf[8];
    __syncthreads();

    for (int t8 = 0; t8 < N_WORDS / 8; ++t8) {
        #pragma unroll
        for (int j = 0; j < 8; ++j) {
            const int t = t8 * 8 + j;
            const int tn = (t + 1) & (N_WORDS - 1);
            // independent global prefetch — stays in flight across the barrier
            float4 xpn = *(const float4*)(xpre + (size_t)tn * 512 + hidx * 4);

            // A operand: h chunk broadcast (all 16 A-rows identical)
            const unsigned char* hb = h8[j & 1] + lg * 32;
            i32x8 bf = *(const i32x8*)hb;          // 2x ds_read_b128

            f32x4 acc[4];
            #pragma unroll
            for (int g = 0; g < 4; ++g) {
                float xg = (g == 0) ? xp.x : (g == 1) ? xp.y : (g == 2) ? xp.z : xp.w;
                f32x4 cxp = {xg, xg, xg, xg};
                acc[g] = __builtin_amdgcn_mfma_scale_f32_16x16x128_f8f6f4(
                    bf, af8[g], cxp, 0, 0, 0, 0x7F7F7F7F, 0, 0x7F7F7F7F);
            }

            float ig = sig2(acc[0][0]);
            float fg = sig2(acc[1][0]);
            float gg = tanh2s(acc[2][0]);
            float og = sig2(acc[3][0]);
            c = fg * c + ig * gg;
            float hn = og * tanhc(c);
            hbuf[j] = hn;
            if (writer) {
                int hp = __builtin_amdgcn_cvt_pk_fp8_f32(hn, hn, 0, false);
                h8[(j + 1) & 1][hidx] = (unsigned char)hp;
            }
            xp = xpn;

            // raw barrier: drain LDS only, leave the global prefetch in flight
            asm volatile("s_waitcnt lgkmcnt(0)" ::: "memory");
            __builtin_amdgcn_sched_barrier(0);
            __builtin_amdgcn_s_barrier();
            __builtin_amdgcn_sched_barrier(0);
        }
        // stores overlap the next step's ds_read latency
        if (writer) {
            #pragma unroll
            for (int jj = 0; jj < 8; ++jj)
                hs[(size_t)(t8 * 8 + jj) * 128 + hidx] = hbuf[jj];
        }
    }
}

// ---------------- Kernel 4: logits + log_softmax, wave per word ------------
extern "C" __global__ void __launch_bounds__(256)
tag_kernel(const float* __restrict__ hs, const float* __restrict__ Wtag,
           const float* __restrict__ btag, float* __restrict__ out)
{
    __shared__ float Wl[64 * 129];
    const int tid = threadIdx.x;
    for (int idx = tid; idx < 64 * 128; idx += 256) {
        int r = idx >> 7, k = idx & 127;
        Wl[r * 129 + k] = Wtag[r * H2 + k];
    }
    __syncthreads();

    const int lane = tid & 63;
    const int word = blockIdx.x * 4 + (tid >> 6);
    const float* hrow = hs + (long)word * H2;
    float acc = btag[lane];
    #pragma unroll 4
    for (int k = 0; k < 128; ++k) acc += Wl[lane * 129 + k] * hrow[k];

    float m = acc;
    #pragma unroll
    for (int off = 32; off > 0; off >>= 1) m = fmaxf(m, __shfl_xor(m, off));
    float e = expf(acc - m);
    float s = e;
    #pragma unroll
    for (int off = 32; off > 0; off >>= 1) s += __shfl_xor(s, off);
    out[(long)word * N_TAGS + lane] = acc - m - logf(s);
}

extern "C" void kernel_launch(void* const* d_in, const int* in_sizes, int n_in,
                              void* d_out, int out_size, void* d_ws, size_t ws_size,
                              hipStream_t stream)
{
    (void)in_sizes; (void)n_in; (void)out_size; (void)ws_size;
    const int*   char_ids  = (const int*)d_in[0];
    const int*   word_ids  = (const int*)d_in[1];
    const int*   char_lens = (const int*)d_in[2];
    const float* char_emb  = (const float*)d_in[3];
    const float* word_emb  = (const float*)d_in[4];
    const float* Wih1 = (const float*)d_in[5];
    const float* Whh1 = (const float*)d_in[6];
    const float* bih1 = (const float*)d_in[7];
    const float* bhh1 = (const float*)d_in[8];
    const float* Wih2 = (const float*)d_in[9];
    const float* Whh2 = (const float*)d_in[10];
    const float* bih2 = (const float*)d_in[11];
    const float* bhh2 = (const float*)d_in[12];
    const float* Wtag = (const float*)d_in[13];
    const float* btag = (const float*)d_in[14];
    float* out = (float*)d_out;

    float* h_char = (float*)d_ws;                          // 16384*64 f32
    float* xpre   = h_char + (size_t)N_WORDS * H1;         // 16384*512 f32 (transposed, x log2e)
    float* hs     = xpre + (size_t)N_WORDS * 512;          // 16384*128 f32
    // prep outputs live in the hs region: consumed by char_lstm BEFORE
    // word_lstm overwrites hs (strict stream order makes this safe).
    _Float16* W16  = (_Float16*)hs;                        // 256*96 f16
    _Float16* ce16 = W16 + 256 * 96;                       // 128*32 f16
    float*    b1s  = (float*)(ce16 + 128 * 32);            // 256 f32

    prep_kernel<<<96, 256, 0, stream>>>(Wih1, Whh1, bih1, bhh1, char_emb,
                                        W16, ce16, b1s);

    char_lstm_kernel<<<N_WORDS / 16, 256, 0, stream>>>(
        char_ids, char_lens, W16, ce16, b1s, h_char);

    dim3 g2(N_WORDS / 32, 8);
    xpre_gemm_kernel<<<g2, 256, 0, stream>>>(
        word_ids, word_emb, h_char, Wih2, bih2, bhh2, xpre);

    word_lstm_kernel<<<1, 512, 0, stream>>>(xpre, Whh2, hs);

    tag_kernel<<<N_WORDS / 4, 256, 0, stream>>>(hs, Wtag, btag, out);
}

// Round 12
// 5477.844 us; speedup vs baseline: 2.0139x; 1.1465x over previous
//
#include <hip/hip_runtime.h>
#include <math.h>

#define N_WORDS 16384
#define MAX_CHARS 16
#define CE 32
#define H1 64
#define WE 64
#define H2 128
#define N_TAGS 64
#define LOG2E 1.44269504f
#define TWO_LOG2E 2.88539008f

typedef _Float16 f16x8 __attribute__((ext_vector_type(8)));
typedef float f32x4 __attribute__((ext_vector_type(4)));
typedef int i32x8 __attribute__((ext_vector_type(8)));

__device__ __forceinline__ float rcpf(float x) { return __builtin_amdgcn_rcpf(x); }
__device__ __forceinline__ float exp2f_hw(float x) { return __builtin_amdgcn_exp2f(x); }
// p pre-scaled by log2e. sig = rcp(1+2^-p); sat exact (rcp(1)=1, rcp(inf)=0).
__device__ __forceinline__ float sig2(float p) { return rcpf(1.0f + exp2f_hw(-p)); }
// tanh given scaled p: 2*sig2(2p)-1
__device__ __forceinline__ float tanh2s(float p) {
    return 2.f * rcpf(1.f + exp2f_hw(-2.f * p)) - 1.f;
}
// tanh of unscaled c: 2*rcp(1+2^(-2*log2e*c))-1; sat exact at +/-1
__device__ __forceinline__ float tanhc(float c) {
    return 2.f * rcpf(1.f + exp2f_hw(-TWO_LOG2E * c)) - 1.f;
}

// ---------------- Kernel 0: prep — f16 weights (scaled by log2e) -----------
extern "C" __global__ void __launch_bounds__(256)
prep_kernel(const float* __restrict__ Wih1, const float* __restrict__ Whh1,
            const float* __restrict__ bih1, const float* __restrict__ bhh1,
            const float* __restrict__ char_emb,
            _Float16* __restrict__ W16, _Float16* __restrict__ ce16,
            float* __restrict__ b1s)
{
    int idx = blockIdx.x * 256 + threadIdx.x;
    if (idx < 256 * 96) {
        int r = idx / 96, k = idx - r * 96;
        float v = (k < CE) ? Wih1[r * CE + k] : Whh1[r * H1 + (k - CE)];
        W16[idx] = (_Float16)(v * LOG2E);
    }
    if (idx < 128 * 32) ce16[idx] = (_Float16)char_emb[idx];
    if (idx < 256) b1s[idx] = (bih1[idx] + bhh1[idx]) * LOG2E;
}

// ---------------- Kernel 1: char LSTM via batched f16 MFMA -----------------
extern "C" __global__ void __launch_bounds__(256)
char_lstm_kernel(const int* __restrict__ char_ids, const int* __restrict__ char_lens,
                 const _Float16* __restrict__ W16, const _Float16* __restrict__ ce16,
                 const float* __restrict__ b1s, float* __restrict__ h_char)
{
    __shared__ _Float16 hl[2][16 * 72];
    const int tid = threadIdx.x;
    const int w  = tid >> 6;        // wave 0..3 -> unit stripe
    const int l  = tid & 63;
    const int lg = l >> 4;          // k-subgroup 0..3
    const int lc = l & 15;          // A-row (word) for A-frags; D-col (unit)
    const int wb = blockIdx.x * 16;

    f16x8 bfr[4][3];
    #pragma unroll
    for (int gt = 0; gt < 4; ++gt)
        #pragma unroll
        for (int kc = 0; kc < 3; ++kc)
            bfr[gt][kc] = *(const f16x8*)(W16 + (size_t)(gt * 64 + 16 * w + lc) * 96
                                          + kc * 32 + lg * 8);
    float bb[4];
    #pragma unroll
    for (int gt = 0; gt < 4; ++gt) bb[gt] = b1s[gt * 64 + 16 * w + lc];

    int cids[16];
    {
        const int4* cp = (const int4*)(char_ids + (size_t)(wb + lc) * 16);
        #pragma unroll
        for (int i = 0; i < 4; ++i) {
            int4 v = cp[i];
            cids[i * 4 + 0] = v.x; cids[i * 4 + 1] = v.y;
            cids[i * 4 + 2] = v.z; cids[i * 4 + 3] = v.w;
        }
    }
    int4 len4 = *(const int4*)(char_lens + wb + lg * 4);
    int lens[4] = {len4.x, len4.y, len4.z, len4.w};

    float hreg[4] = {0.f, 0.f, 0.f, 0.f};
    float creg[4] = {0.f, 0.f, 0.f, 0.f};
    for (int i = tid; i < 16 * 72; i += 256) hl[0][i] = (_Float16)0.f;
    __syncthreads();

    #pragma unroll
    for (int t = 0; t < MAX_CHARS; ++t) {
        const _Float16* hb = hl[t & 1];
        f16x8 ax  = *(const f16x8*)(ce16 + (size_t)cids[t] * 32 + lg * 8);
        f16x8 ah1 = *(const f16x8*)(hb + lc * 72 + lg * 8);
        f16x8 ah2 = *(const f16x8*)(hb + lc * 72 + 32 + lg * 8);
        f32x4 acc[4];
        #pragma unroll
        for (int gt = 0; gt < 4; ++gt) {
            f32x4 cb = {bb[gt], bb[gt], bb[gt], bb[gt]};
            acc[gt] = __builtin_amdgcn_mfma_f32_16x16x32_f16(ax,  bfr[gt][0], cb, 0, 0, 0);
            acc[gt] = __builtin_amdgcn_mfma_f32_16x16x32_f16(ah1, bfr[gt][1], acc[gt], 0, 0, 0);
            acc[gt] = __builtin_amdgcn_mfma_f32_16x16x32_f16(ah2, bfr[gt][2], acc[gt], 0, 0, 0);
        }
        #pragma unroll
        for (int q = 0; q < 4; ++q) {
            float ig = sig2(acc[0][q]);
            float fg = sig2(acc[1][q]);
            float gg = tanh2s(acc[2][q]);
            float og = sig2(acc[3][q]);
            float cn = fg * creg[q] + ig * gg;
            float hn = og * tanhc(cn);
            bool v = t < lens[q];
            creg[q] = v ? cn : creg[q];
            hreg[q] = v ? hn : hreg[q];
            hl[(t + 1) & 1][(lg * 4 + q) * 72 + 16 * w + lc] = (_Float16)hreg[q];
        }
        __syncthreads();
    }
    #pragma unroll
    for (int q = 0; q < 4; ++q)
        h_char[(size_t)(wb + lg * 4 + q) * H1 + 16 * w + lc] = hreg[q];
}

// ---------------- Kernel 2: xpre = [word_emb | h_char] @ Wih2^T + b2 --------
// OUTPUT TRANSPOSED + scaled by log2e: xpre_t[t][hid*4+g] (g=col>>7, hid=col&127)
extern "C" __global__ void __launch_bounds__(256)
xpre_gemm_kernel(const int* __restrict__ word_ids, const float* __restrict__ word_emb,
                 const float* __restrict__ h_char,
                 const float* __restrict__ Wih2,
                 const float* __restrict__ bih2, const float* __restrict__ bhh2,
                 float* __restrict__ xpre)
{
    __shared__ float Wl[64 * 130];
    __shared__ float Xl[32 * 130];
    const int tid = threadIdx.x;
    const int wb = blockIdx.x * 32;   // word base
    const int cb = blockIdx.y * 64;   // col base

    for (int idx = tid; idx < 64 * 128; idx += 256) {
        int r = idx >> 7, k = idx & 127;
        Wl[r * 130 + k] = Wih2[(cb + r) * H2 + k];
    }
    for (int idx = tid; idx < 32 * 128; idx += 256) {
        int w = idx >> 7, k = idx & 127;
        float v = (k < WE) ? word_emb[(long)word_ids[wb + w] * WE + k]
                           : h_char[(long)(wb + w) * H1 + (k - WE)];
        Xl[w * 130 + k] = v;
    }
    __syncthreads();

    const int tc = tid & 31;
    const int wg = tid >> 5;          // 0..7
    float acc[4][2] = {};
    for (int k = 0; k < 128; ++k) {
        float wv0 = Wl[tc * 130 + k];
        float wv1 = Wl[(tc + 32) * 130 + k];
        #pragma unroll
        for (int i = 0; i < 4; ++i) {
            float x = Xl[(wg * 4 + i) * 130 + k];
            acc[i][0] += x * wv0;
            acc[i][1] += x * wv1;
        }
    }
    int c0 = cb + tc, c1 = cb + tc + 32;
    float b0 = bih2[c0] + bhh2[c0];
    float b1v = bih2[c1] + bhh2[c1];
    int o0 = (c0 & 127) * 4 + (c0 >> 7);
    int o1 = (c1 & 127) * 4 + (c1 >> 7);
    #pragma unroll
    for (int i = 0; i < 4; ++i) {
        long w = wb + wg * 4 + i;
        xpre[w * 512 + o0] = (acc[i][0] + b0) * LOG2E;
        xpre[w * 512 + o1] = (acc[i][1] + b1v) * LOG2E;
    }
}

// ---------------- Kernel 3: word LSTM, fp8 K=128 MFMA, gate-split ----------
// Wave w owns units [16w,16w+16). lg-group g computes ONLY gate g's
// transcendental (unified val = ga*rcp(1+2^(-gs*p))+gb); 3 __shfl gather
// f,g,o into lg=0 writer lanes which run the c/h tail. xp is one scalar
// per lane. C operand = 0 (fold reverted). One barrier/step.
extern "C" __global__ void __launch_bounds__(512)
word_lstm_kernel(const float* __restrict__ xpre, const float* __restrict__ Whh2,
                 float* __restrict__ hs)
{
    __shared__ __align__(16) unsigned char h8[2][128];
    const int tid = threadIdx.x;
    const int w   = tid >> 6;      // wave 0..7
    const int l   = tid & 63;
    const int lg  = l >> 4;        // gate index this lane evaluates
    const int lc  = l & 15;        // unit within wave block
    const int hidx = 16 * w + lc;  // this lane's unit [0,128)
    const bool writer = (l < 16);

    // unified gate constants: gate 2 (g) is tanh = 2*sig(2p)-1
    const float gs = (lg == 2) ? 2.f : 1.f;
    const float ga = (lg == 2) ? 2.f : 1.f;
    const float gb = (lg == 2) ? -1.f : 0.f;

    // U^T fragments fp8 (B operand), scaled by log2e before quantization
    i32x8 af8[4];
    #pragma unroll
    for (int g = 0; g < 4; ++g) {
        const float* wrow = Whh2 + (size_t)(g * 128 + hidx) * 128 + lg * 32;
        i32x8 a;
        #pragma unroll
        for (int r = 0; r < 8; ++r) {
            int pk = __builtin_amdgcn_cvt_pk_fp8_f32(
                wrow[r * 4 + 0] * LOG2E, wrow[r * 4 + 1] * LOG2E, 0, false);
            pk = __builtin_amdgcn_cvt_pk_fp8_f32(
                wrow[r * 4 + 2] * LOG2E, wrow[r * 4 + 3] * LOG2E, pk, true);
            a[r] = pk;
        }
        af8[g] = a;
    }
    if (tid < 128) h8[0][tid] = 0;
    float c = 0.f;
    const float* xq_base = xpre + 64 * w + 4 * lc + lg;  // this lane's gate scalar
    float xq = xq_base[0];                               // t = 0
    float hbuf[8];
    const f32x4 zf = {0.f, 0.f, 0.f, 0.f};
    __syncthreads();

    for (int t8 = 0; t8 < N_WORDS / 8; ++t8) {
        #pragma unroll
        for (int j = 0; j < 8; ++j) {
            const int t = t8 * 8 + j;
            const int tn = (t + 1) & (N_WORDS - 1);
            // scalar prefetch — stays in flight across the barrier
            float xqn = xq_base[(size_t)tn * 512];

            // A operand: h chunk broadcast (all 16 A-rows identical)
            const unsigned char* hb = h8[j & 1] + lg * 32;
            i32x8 bf = *(const i32x8*)hb;          // 2x ds_read_b128

            f32x4 acc[4];
            #pragma unroll
            for (int g = 0; g < 4; ++g)
                acc[g] = __builtin_amdgcn_mfma_scale_f32_16x16x128_f8f6f4(
                    bf, af8[g], zf, 0, 0, 0, 0x7F7F7F7F, 0, 0x7F7F7F7F);

            // this lane's gate only
            float pv = (lg == 0) ? acc[0][0] : (lg == 1) ? acc[1][0]
                     : (lg == 2) ? acc[2][0] : acc[3][0];
            float p = pv + xq;
            float myv = ga * rcpf(1.f + exp2f_hw(-gs * p)) + gb;

            // gather f,g,o into lg=0 lanes (addresses loop-invariant)
            float fv = __shfl(myv, lc + 16);
            float gv = __shfl(myv, lc + 32);
            float ov = __shfl(myv, lc + 48);

            if (writer) {                     // lg==0: myv is the i-gate
                c = fv * c + myv * gv;
                float hn = ov * tanhc(c);
                hbuf[j] = hn;
                int hp = __builtin_amdgcn_cvt_pk_fp8_f32(hn, hn, 0, false);
                h8[(j + 1) & 1][hidx] = (unsigned char)hp;
            }
            xq = xqn;

            // raw barrier: drain LDS only, leave the global prefetch in flight
            asm volatile("s_waitcnt lgkmcnt(0)" ::: "memory");
            __builtin_amdgcn_sched_barrier(0);
            __builtin_amdgcn_s_barrier();
            __builtin_amdgcn_sched_barrier(0);
        }
        // stores overlap the next step's ds_read latency
        if (writer) {
            #pragma unroll
            for (int jj = 0; jj < 8; ++jj)
                hs[(size_t)(t8 * 8 + jj) * 128 + hidx] = hbuf[jj];
        }
    }
}

// ---------------- Kernel 4: logits + log_softmax, wave per word ------------
extern "C" __global__ void __launch_bounds__(256)
tag_kernel(const float* __restrict__ hs, const float* __restrict__ Wtag,
           const float* __restrict__ btag, float* __restrict__ out)
{
    __shared__ float Wl[64 * 129];
    const int tid = threadIdx.x;
    for (int idx = tid; idx < 64 * 128; idx += 256) {
        int r = idx >> 7, k = idx & 127;
        Wl[r * 129 + k] = Wtag[r * H2 + k];
    }
    __syncthreads();

    const int lane = tid & 63;
    const int word = blockIdx.x * 4 + (tid >> 6);
    const float* hrow = hs + (long)word * H2;
    float acc = btag[lane];
    #pragma unroll 4
    for (int k = 0; k < 128; ++k) acc += Wl[lane * 129 + k] * hrow[k];

    float m = acc;
    #pragma unroll
    for (int off = 32; off > 0; off >>= 1) m = fmaxf(m, __shfl_xor(m, off));
    float e = expf(acc - m);
    float s = e;
    #pragma unroll
    for (int off = 32; off > 0; off >>= 1) s += __shfl_xor(s, off);
    out[(long)word * N_TAGS + lane] = acc - m - logf(s);
}

extern "C" void kernel_launch(void* const* d_in, const int* in_sizes, int n_in,
                              void* d_out, int out_size, void* d_ws, size_t ws_size,
                              hipStream_t stream)
{
    (void)in_sizes; (void)n_in; (void)out_size; (void)ws_size;
    const int*   char_ids  = (const int*)d_in[0];
    const int*   word_ids  = (const int*)d_in[1];
    const int*   char_lens = (const int*)d_in[2];
    const float* char_emb  = (const float*)d_in[3];
    const float* word_emb  = (const float*)d_in[4];
    const float* Wih1 = (const float*)d_in[5];
    const float* Whh1 = (const float*)d_in[6];
    const float* bih1 = (const float*)d_in[7];
    const float* bhh1 = (const float*)d_in[8];
    const float* Wih2 = (const float*)d_in[9];
    const float* Whh2 = (const float*)d_in[10];
    const float* bih2 = (const float*)d_in[11];
    const float* bhh2 = (const float*)d_in[12];
    const float* Wtag = (const float*)d_in[13];
    const float* btag = (const float*)d_in[14];
    float* out = (float*)d_out;

    float* h_char = (float*)d_ws;                          // 16384*64 f32
    float* xpre   = h_char + (size_t)N_WORDS * H1;         // 16384*512 f32 (transposed, x log2e)
    float* hs     = xpre + (size_t)N_WORDS * 512;          // 16384*128 f32
    // prep outputs live in the hs region: consumed by char_lstm BEFORE
    // word_lstm overwrites hs (strict stream order makes this safe).
    _Float16* W16  = (_Float16*)hs;                        // 256*96 f16
    _Float16* ce16 = W16 + 256 * 96;                       // 128*32 f16
    float*    b1s  = (float*)(ce16 + 128 * 32);            // 256 f32

    prep_kernel<<<96, 256, 0, stream>>>(Wih1, Whh1, bih1, bhh1, char_emb,
                                        W16, ce16, b1s);

    char_lstm_kernel<<<N_WORDS / 16, 256, 0, stream>>>(
        char_ids, char_lens, W16, ce16, b1s, h_char);

    dim3 g2(N_WORDS / 32, 8);
    xpre_gemm_kernel<<<g2, 256, 0, stream>>>(
        word_ids, word_emb, h_char, Wih2, bih2, bhh2, xpre);

    word_lstm_kernel<<<1, 512, 0, stream>>>(xpre, Whh2, hs);

    tag_kernel<<<N_WORDS / 4, 256, 0, stream>>>(hs, Wtag, btag, out);
}